// Round 8
// baseline (262.363 us; speedup 1.0000x reference)
//
#include <hip/hip_runtime.h>

#define NN 16512      // N = K + EXER nodes
#define KK 128        // feature dim
#define K3 384        // 3 graphs concatenated along K
#define EE 262144     // edges per graph
#define BB 2048       // batch
#define HH 64         // history length
#define NKf ((size_t)NN * KK)
#define NB 64         // hist blocks per graph
#define EPB (EE / NB) // 4096 edges per block
#define NP (NN / 2)   // 8256 packed u16-pair counters
#define RPB 16        // rows per k_layer block

typedef unsigned int u32;
typedef unsigned short u16;
typedef unsigned long long u64;
typedef short bf16x8 __attribute__((ext_vector_type(8)));
typedef float f32x4 __attribute__((ext_vector_type(4)));

__device__ __forceinline__ float sgm(float x) { return 1.0f / (1.0f + __expf(-x)); }

__device__ __forceinline__ u16 f2bf(float f) {          // round-to-nearest-even
  u32 u = __float_as_uint(f);
  u32 r = u + 0x7fffu + ((u >> 16) & 1u);
  return (u16)(r >> 16);
}
__device__ __forceinline__ float bflo(u32 p) { return __uint_as_float(p << 16); }
__device__ __forceinline__ float bfhi(u32 p) { return __uint_as_float(p & 0xffff0000u); }

// ---- nontemporal helpers (keep x hot in L2 by not caching streams) ----
__device__ __forceinline__ int   ntld_i(const int* p)   { return __builtin_nontemporal_load(p); }
__device__ __forceinline__ u32   ntld_u(const u32* p)   { return __builtin_nontemporal_load(p); }
__device__ __forceinline__ float ntld_f(const float* p) { return __builtin_nontemporal_load(p); }
__device__ __forceinline__ uint2 ntld_u2(const uint2* p) {
  u64 v = __builtin_nontemporal_load((const u64*)p);
  return make_uint2((u32)v, (u32)(v >> 32));
}
__device__ __forceinline__ f32x4 ntld_f4(const float* p) {
  return __builtin_nontemporal_load((const f32x4*)p);
}
__device__ __forceinline__ void ntst_f(float* p, float v)  { __builtin_nontemporal_store(v, p); }
__device__ __forceinline__ void ntst_u16(u16* p, u16 v)    { __builtin_nontemporal_store(v, p); }
__device__ __forceinline__ void ntst_u(u32* p, u32 v)      { __builtin_nontemporal_store(v, p); }
__device__ __forceinline__ void ntst_u2(uint2* p, uint2 v) {
  u64 w = ((u64)v.y << 32) | v.x;
  __builtin_nontemporal_store(w, (u64*)p);
}

// ---------------- graph preprocessing (atomic-free counting sort) ----------------

__global__ __launch_bounds__(256) void k_hist(
    const int* __restrict__ s0, const int* __restrict__ d0,
    const int* __restrict__ s1, const int* __restrict__ d1,
    const int* __restrict__ s2, const int* __restrict__ d2,
    u32* __restrict__ slabO, u32* __restrict__ slabI) {
  int g = blockIdx.y, b = blockIdx.x;
  const int* src = g == 0 ? s0 : (g == 1 ? s1 : s2);
  const int* dst = g == 0 ? d0 : (g == 1 ? d1 : d2);
  __shared__ u32 hO[NP], hI[NP];
  for (int i = threadIdx.x; i < NP; i += 256) { hO[i] = 0; hI[i] = 0; }
  __syncthreads();
  int base = b * EPB;
  for (int i = threadIdx.x; i < EPB; i += 256) {
    int s = ntld_i(src + base + i), d = ntld_i(dst + base + i);
    atomicAdd(&hO[s >> 1], 1u << ((s & 1) * 16));
    atomicAdd(&hI[d >> 1], 1u << ((d & 1) * 16));
  }
  __syncthreads();
  u32* oO = slabO + ((size_t)g * NB + b) * NP;
  u32* oI = slabI + ((size_t)g * NB + b) * NP;
  for (int i = threadIdx.x; i < NP; i += 256) { ntst_u(oO + i, hO[i]); ntst_u(oI + i, hI[i]); }
}

__global__ void k_reduce(u32* __restrict__ slabO, u32* __restrict__ slabI,
                         u32* __restrict__ degI, float* __restrict__ rsdO,
                         float* __restrict__ rsdI) {
  int g = blockIdx.y;
  int t = blockIdx.x * 256 + threadIdx.x;
  if (t >= NP) return;
  u32* sO = slabO + (size_t)g * NB * NP + t;
  u32* sI = slabI + (size_t)g * NB * NP + t;
  u32 sumO = 0, pre = 0;
  #pragma unroll 8
  for (int b = 0; b < NB; ++b) sumO += ntld_u(sO + (size_t)b * NP);
  #pragma unroll 8
  for (int b = 0; b < NB; ++b) {
    u32 v = ntld_u(sI + (size_t)b * NP);
    ntst_u(sI + (size_t)b * NP, pre);   // packed u16 exclusive prefix
    pre += v;
  }
  u32 dOl = sumO & 0xffffu, dOh = sumO >> 16;
  u32 dIl = pre & 0xffffu,  dIh = pre >> 16;
  *(uint2*)(degI + (size_t)g * NN + 2 * t) = make_uint2(dIl, dIh);
  *(float2*)(rsdO + (size_t)g * NN + 2 * t) =
      make_float2(rsqrtf((float)(dOl ? dOl : 1u)), rsqrtf((float)(dOh ? dOh : 1u)));
  *(float2*)(rsdI + (size_t)g * NN + 2 * t) =
      make_float2(rsqrtf((float)(dIl ? dIl : 1u)), rsqrtf((float)(dIh ? dIh : 1u)));
}

__global__ __launch_bounds__(1024) void k_exscan2(const u32* __restrict__ degI,
                                                  u32* __restrict__ rps) {
  int g = blockIdx.x;
  const u32* deg = degI + (size_t)g * NN;
  u32* rp = rps + (size_t)g * (NN + 1);
  int t = threadIdx.x;
  int i0 = t * 17, i1 = i0 + 17 < NN ? i0 + 17 : NN;
  u32 s = 0;
  for (int i = i0; i < i1; ++i) s += deg[i];
  u32 x = s;
  int lane = t & 63, wid = t >> 6;
  #pragma unroll
  for (int off = 1; off < 64; off <<= 1) {
    u32 y = __shfl_up(x, off);
    if (lane >= off) x += y;
  }
  __shared__ u32 wsums[16];
  if (lane == 63) wsums[wid] = x;
  __syncthreads();
  if (t == 0) {
    u32 run = 0;
    #pragma unroll
    for (int i = 0; i < 16; ++i) { u32 tmp = wsums[i]; wsums[i] = run; run += tmp; }
  }
  __syncthreads();
  u32 run = wsums[wid] + x - s;
  for (int i = i0; i < i1; ++i) { rp[i] = run; run += deg[i]; }
  if (t == 0) rp[NN] = EE;
}

// edata[idx] = { src, norm(f32) } -> single 8B NT store per edge
__global__ __launch_bounds__(256) void k_scatter2(
    const int* __restrict__ s0, const int* __restrict__ d0,
    const int* __restrict__ s1, const int* __restrict__ d1,
    const int* __restrict__ s2, const int* __restrict__ d2,
    const u32* __restrict__ slabI, const u32* __restrict__ rps,
    const float* __restrict__ rsdO, const float* __restrict__ rsdI,
    uint2* __restrict__ edatas) {
  int g = blockIdx.y, b = blockIdx.x;
  const int* src = g == 0 ? s0 : (g == 1 ? s1 : s2);
  const int* dst = g == 0 ? d0 : (g == 1 ? d1 : d2);
  const u32* rp = rps + (size_t)g * (NN + 1);
  const u32* pre = slabI + ((size_t)g * NB + b) * NP;
  const float* rO = rsdO + (size_t)g * NN;
  const float* rI = rsdI + (size_t)g * NN;
  uint2* ed = edatas + (size_t)g * EE;
  __shared__ u32 cur[NN];
  for (int i = threadIdx.x; i < NP; i += 256) {
    u32 p = ntld_u(pre + i);
    cur[2 * i]     = rp[2 * i] + (p & 0xffffu);
    cur[2 * i + 1] = rp[2 * i + 1] + (p >> 16);
  }
  __syncthreads();
  int base = b * EPB;
  for (int i = threadIdx.x; i < EPB; i += 256) {
    int s = ntld_i(src + base + i), d = ntld_i(dst + base + i);
    u32 idx = atomicAdd(&cur[d], 1u);
    ntst_u2(ed + idx, make_uint2((u32)s, __float_as_uint(rO[s] * rI[d])));
  }
}

// ---------------- fused prep: entity->bf16 | W pre-swizzle | bias sums ----------------
// Bsw[((l*96 + nb*12 + ks)*64 + lane)*8 + j] = bf16( W[l, g, kin, kout] )
//   k = ks*32 + (lane>>4)*8 + j ; g = k>>7 ; kin = k&127 ; kout = nb*16 + (lane&15)

__global__ void k_prep(const float* __restrict__ entity, u16* __restrict__ xent,
                       const float* __restrict__ W, u16* __restrict__ Bsw,
                       const float* __restrict__ b, float* __restrict__ bsum) {
  int bid = blockIdx.x;
  if (bid < 1032) {                       // cvt: NN*KK/8 = 264192 items
    int t = bid * 256 + threadIdx.x;
    if (t >= NN * KK / 8) return;
    f32x4 v0 = ntld_f4(entity + (size_t)t * 8);
    f32x4 v1 = ntld_f4(entity + (size_t)t * 8 + 4);
    bf16x8 o;
    o[0] = (short)f2bf(v0[0]); o[1] = (short)f2bf(v0[1]);
    o[2] = (short)f2bf(v0[2]); o[3] = (short)f2bf(v0[3]);
    o[4] = (short)f2bf(v1[0]); o[5] = (short)f2bf(v1[1]);
    o[6] = (short)f2bf(v1[2]); o[7] = (short)f2bf(v1[3]);
    *(bf16x8*)(xent + (size_t)t * 8) = o;
  } else if (bid < 1104) {                // prepB: 18432 items
    int t = (bid - 1032) * 256 + threadIdx.x;
    if (t >= 3 * 8 * 12 * 64) return;
    int lane = t & 63;
    int ks = (t >> 6) % 12;
    int nb = ((t >> 6) / 12) % 8;
    int l  = (t >> 6) / 96;
    int kout = nb * 16 + (lane & 15);
    int kb = ks * 32 + (lane >> 4) * 8;
    bf16x8 v;
    #pragma unroll
    for (int j = 0; j < 8; ++j) {
      int k = kb + j; int g = k >> 7; int kin = k & 127;
      v[j] = (short)f2bf(W[(((size_t)l * 3 + g) * KK + kin) * KK + kout]);
    }
    *(bf16x8*)(Bsw + (size_t)t * 8) = v;
  } else {                                // bias sums: 384 items
    int t = (bid - 1104) * 256 + threadIdx.x;
    if (t >= 3 * KK) return;
    int l = t >> 7, c = t & 127;
    bsum[l * KK + c] = b[(l * 3 + 0) * KK + c] + b[(l * 3 + 1) * KK + c] + b[(l * 3 + 2) * KK + c];
  }
}

// ---------------- fused layer: SpMM (3 graphs -> LDS) + MFMA GEMM + epilogue ----------
// Block owns 16 rows; 8 waves; 48 row-tasks processed as 24 PAIRS (2 independent
// gather chains per wave -> 2x MLP). Edge meta read directly (NT) - no staging.
// mode: 1 = Sx = entity + v ; else Sx += v
//       2 = Ss = v ; 4 = Ssb = bf16(Ss + v) ; 8 = skip h write

#define ACC8(A, P, N)                                              \
  A[0] += bflo(P.x) * N; A[1] += bfhi(P.x) * N;                    \
  A[2] += bflo(P.y) * N; A[3] += bfhi(P.y) * N;                    \
  A[4] += bflo(P.z) * N; A[5] += bfhi(P.z) * N;                    \
  A[6] += bflo(P.w) * N; A[7] += bfhi(P.w) * N;

#define ONE(ED, E, A) {                                            \
    uint2 m = ntld_u2(ED + E + slot);                              \
    float n = __uint_as_float(m.y);                                \
    uint4 p = *(const uint4*)(x + (size_t)m.x * KK + cg * 8);      \
    ACC8(A, p, n) }

__global__ __launch_bounds__(512, 8) void k_layer(
    const u16* __restrict__ x, const u32* __restrict__ rps,
    const uint2* __restrict__ edatas, const u16* __restrict__ Bsw,
    const float* __restrict__ bsum, u16* __restrict__ hout,
    const float* __restrict__ entity, float* __restrict__ Sx,
    float* __restrict__ Ss, u16* __restrict__ Ssb, int mode)
{
  __shared__ u16 At[RPB][392];            // 12.25 KB; row stride 784B -> 2-way (free)
  __shared__ u32 rpl[3][RPB + 1];         // row pointers
  const int tid = threadIdx.x;
  const int wv = tid >> 6, lane = tid & 63;
  const int m0 = blockIdx.x * RPB;
  const int slot = lane >> 4, cg = lane & 15;

  if (tid < 3 * (RPB + 1))
    rpl[tid / (RPB + 1)][tid % (RPB + 1)] =
        rps[(size_t)(tid / (RPB + 1)) * (NN + 1) + m0 + tid % (RPB + 1)];
  __syncthreads();

  // ---- SpMM phase: 24 pairs, 2 independent chains per wave ----
  for (int p = wv; p < 24; p += 8) {
    int tA = p, tB = p + 24;
    int gA = tA >> 4, rA = tA & 15;
    int gB = tB >> 4, rB = tB & 15;
    u32 begA = rpl[gA][rA], cntA = rpl[gA][rA + 1] - begA;
    u32 begB = rpl[gB][rB], cntB = rpl[gB][rB + 1] - begB;
    const uint2* edA = edatas + (size_t)gA * EE + begA;
    const uint2* edB = edatas + (size_t)gB * EE + begB;
    float accA[8] = {0.f, 0.f, 0.f, 0.f, 0.f, 0.f, 0.f, 0.f};
    float accB[8] = {0.f, 0.f, 0.f, 0.f, 0.f, 0.f, 0.f, 0.f};
    u32 qA = cntA & ~3u, qB = cntB & ~3u;
    u32 qm = qA < qB ? qA : qB;
    u32 eA = 0, eB = 0;
    for (; eA < qm; eA += 4, eB += 4) {
      uint2 mA = ntld_u2(edA + eA + slot);
      uint2 mB = ntld_u2(edB + eB + slot);
      uint4 pA = *(const uint4*)(x + (size_t)mA.x * KK + cg * 8);
      uint4 pB = *(const uint4*)(x + (size_t)mB.x * KK + cg * 8);
      float nA = __uint_as_float(mA.y), nB = __uint_as_float(mB.y);
      ACC8(accA, pA, nA) ACC8(accB, pB, nB)
    }
    for (; eA < qA; eA += 4) ONE(edA, eA, accA)
    for (; eB < qB; eB += 4) ONE(edB, eB, accB)
    if (eA + slot < cntA) ONE(edA, eA, accA)
    if (eB + slot < cntB) ONE(edB, eB, accB)
    #pragma unroll
    for (int i = 0; i < 8; ++i) {
      accA[i] += __shfl_xor(accA[i], 16); accA[i] += __shfl_xor(accA[i], 32);
      accB[i] += __shfl_xor(accB[i], 16); accB[i] += __shfl_xor(accB[i], 32);
    }
    if (slot == 0) {
      u32 a0 = ((u32)f2bf(accA[1]) << 16) | (u32)f2bf(accA[0]);
      u32 a1 = ((u32)f2bf(accA[3]) << 16) | (u32)f2bf(accA[2]);
      u32 a2 = ((u32)f2bf(accA[5]) << 16) | (u32)f2bf(accA[4]);
      u32 a3 = ((u32)f2bf(accA[7]) << 16) | (u32)f2bf(accA[6]);
      *(uint4*)(&At[rA][gA * KK + cg * 8]) = make_uint4(a0, a1, a2, a3);
      u32 b0 = ((u32)f2bf(accB[1]) << 16) | (u32)f2bf(accB[0]);
      u32 b1 = ((u32)f2bf(accB[3]) << 16) | (u32)f2bf(accB[2]);
      u32 b2 = ((u32)f2bf(accB[5]) << 16) | (u32)f2bf(accB[4]);
      u32 b3 = ((u32)f2bf(accB[7]) << 16) | (u32)f2bf(accB[6]);
      *(uint4*)(&At[rB][gB * KK + cg * 8]) = make_uint4(b0, b1, b2, b3);
    }
  }
  __syncthreads();

  // ---- MFMA phase: 16x128 = At(16x384) @ B(384x128); wave wv -> cols wv*16.. ----
  const int lr = lane & 15, lk = lane >> 4;
  f32x4 acc2 = {0.f, 0.f, 0.f, 0.f};
  const u16* aB = Bsw + (size_t)wv * 6144 + (size_t)lane * 8;
  #pragma unroll
  for (int ks = 0; ks < 12; ++ks) {
    bf16x8 a = *(const bf16x8*)(&At[lr][ks * 32 + lk * 8]);
    bf16x8 b = *(const bf16x8*)(aB + ks * 512);
    acc2 = __builtin_amdgcn_mfma_f32_16x16x32_bf16(a, b, acc2, 0, 0, 0);
  }

  int col = wv * 16 + lr;
  float bv = bsum[col];
  int rowb = m0 + lk * 4;
  #pragma unroll
  for (int r = 0; r < 4; ++r) {
    size_t idx = (size_t)(rowb + r) * KK + col;
    float v = acc2[r] + bv;
    if (!(mode & 8)) ntst_u16(&hout[idx], f2bf(v));
    float sx = (mode & 1) ? (ntld_f(&entity[idx]) + v) : (ntld_f(&Sx[idx]) + v);
    ntst_f(&Sx[idx], sx);
    if (mode & 2) ntst_f(&Ss[idx], v);
    else if (mode & 4) ntst_u16(&Ssb[idx], f2bf(ntld_f(&Ss[idx]) + v));
  }
}

// ---------------- fused post: history mean (quad rows) + concept projections ----------

__global__ __launch_bounds__(256) void k_post(
    const u16* __restrict__ Ssb, const int* __restrict__ hist, const int* __restrict__ hlen,
    float* __restrict__ semb, const float* __restrict__ Sx,
    const float* __restrict__ Wstu, const float* __restrict__ Wexer,
    float* __restrict__ cstu, float* __restrict__ cexer)
{
  int wv = threadIdx.x >> 6, lane = threadIdx.x & 63;
  if (blockIdx.x < 512) {                 // stuemb: 2048 items
    int item = blockIdx.x * 4 + wv;
    int slot = lane >> 4, cg = lane & 15;
    int len = hlen[item];
    const int* hrow = hist + item * HH;
    float acc[8] = {0.f, 0.f, 0.f, 0.f, 0.f, 0.f, 0.f, 0.f};
    int h = 0;
    for (; h + 4 <= len; h += 4) {
      int id = ntld_i(hrow + h + slot);
      uint4 p = *(const uint4*)(Ssb + (size_t)(KK + id) * KK + cg * 8);
      acc[0] += bflo(p.x); acc[1] += bfhi(p.x);
      acc[2] += bflo(p.y); acc[3] += bfhi(p.y);
      acc[4] += bflo(p.z); acc[5] += bfhi(p.z);
      acc[6] += bflo(p.w); acc[7] += bfhi(p.w);
    }
    if (h + slot < len) {
      int id = ntld_i(hrow + h + slot);
      uint4 p = *(const uint4*)(Ssb + (size_t)(KK + id) * KK + cg * 8);
      acc[0] += bflo(p.x); acc[1] += bfhi(p.x);
      acc[2] += bflo(p.y); acc[3] += bfhi(p.y);
      acc[4] += bflo(p.z); acc[5] += bfhi(p.z);
      acc[6] += bflo(p.w); acc[7] += bfhi(p.w);
    }
    #pragma unroll
    for (int i = 0; i < 8; ++i) {
      acc[i] += __shfl_xor(acc[i], 16);
      acc[i] += __shfl_xor(acc[i], 32);
    }
    if (slot == 0) {
      float sc = 0.5f / (float)len;
      float4 o0 = make_float4(acc[0] * sc, acc[1] * sc, acc[2] * sc, acc[3] * sc);
      float4 o1 = make_float4(acc[4] * sc, acc[5] * sc, acc[6] * sc, acc[7] * sc);
      *(float4*)(semb + (size_t)item * KK + cg * 8) = o0;
      *(float4*)(semb + (size_t)item * KK + cg * 8 + 4) = o1;
    }
  } else {                                // cproj: 128 concept rows
    int w = (blockIdx.x - 512) * 4 + wv;
    float2 c = *(const float2*)(Sx + (size_t)w * KK + lane * 2);
    c.x *= 0.25f; c.y *= 0.25f;
    float2 ws = *(const float2*)(Wstu + KK + lane * 2);
    float2 we = *(const float2*)(Wexer + KK + lane * 2);
    float ps = c.x * ws.x + c.y * ws.y;
    float pe = c.x * we.x + c.y * we.y;
    #pragma unroll
    for (int off = 32; off; off >>= 1) { ps += __shfl_xor(ps, off); pe += __shfl_xor(pe, off); }
    if (lane == 0) { cstu[w] = ps; cexer[w] = pe; }
  }
}

__global__ void k_final(const float* __restrict__ Sx, const float* __restrict__ semb,
                        const float* __restrict__ cstu, const float* __restrict__ cexer,
                        const float* __restrict__ Wstu, const float* __restrict__ Wexer,
                        const float* __restrict__ W3, const float* __restrict__ disc,
                        const int* __restrict__ exid, const float* __restrict__ kn,
                        const float* __restrict__ bstu, const float* __restrict__ bexer,
                        const float* __restrict__ b3, float* __restrict__ out) {
  int w = (blockIdx.x * 256 + threadIdx.x) >> 6;   // batch index
  int lane = threadIdx.x & 63;
  if (w >= BB) return;
  int eid = exid[w];
  float2 se = *(const float2*)(Sx + ((size_t)(KK + eid)) * KK + lane * 2);
  se.x *= 0.25f; se.y *= 0.25f;                    // exer_emb
  float2 sm = *(const float2*)(semb + (size_t)w * KK + lane * 2);
  float2 ws = *(const float2*)(Wstu + lane * 2);
  float2 we = *(const float2*)(Wexer + lane * 2);
  float ps = sm.x * ws.x + sm.y * ws.y;
  float pe = se.x * we.x + se.y * we.y;
  #pragma unroll
  for (int off = 32; off; off >>= 1) { ps += __shfl_xor(ps, off); pe += __shfl_xor(pe, off); }
  float s_stu = ps + bstu[0];
  float s_exer = pe + bexer[0];
  float ed = 10.f * sgm(disc[eid]);
  float2 cs = *(const float2*)(cstu + lane * 2);
  float2 ce = *(const float2*)(cexer + lane * 2);
  float2 knv = *(const float2*)(kn + (size_t)w * KK + lane * 2);
  float x0 = ed * (sgm(s_stu + cs.x) - sgm(s_exer + ce.x)) * knv.x;
  float x1 = ed * (sgm(s_stu + cs.y) - sgm(s_exer + ce.y)) * knv.y;
  float2 w3v = *(const float2*)(W3 + lane * 2);
  float px = x0 * w3v.x + x1 * w3v.y;
  #pragma unroll
  for (int off = 32; off; off >>= 1) px += __shfl_xor(px, off);
  if (lane == 0) out[w] = sgm(px + b3[0]);
}

// ---------------- host ----------------

extern "C" void kernel_launch(void* const* d_in, const int* in_sizes, int n_in,
                              void* d_out, int out_size, void* d_ws, size_t ws_size,
                              hipStream_t stream)
{
  const float* entity = (const float*)d_in[0];
  const float* gcnW   = (const float*)d_in[1];
  const float* gcnB   = (const float*)d_in[2];
  const float* disc   = (const float*)d_in[3];
  const float* Wstu   = (const float*)d_in[4];
  const float* bstu   = (const float*)d_in[5];
  const float* Wexer  = (const float*)d_in[6];
  const float* bexer  = (const float*)d_in[7];
  const float* W3     = (const float*)d_in[8];
  const float* b3     = (const float*)d_in[9];
  const float* kn     = (const float*)d_in[10];
  const int* exer_id  = (const int*)d_in[12];
  const int* history  = (const int*)d_in[14];
  const int* hlen     = (const int*)d_in[15];
  const int* s0 = (const int*)d_in[16], *dd0 = (const int*)d_in[17];
  const int* s1 = (const int*)d_in[18], *dd1 = (const int*)d_in[19];
  const int* s2 = (const int*)d_in[20], *dd2 = (const int*)d_in[21];

  char* ws = (char*)d_ws;
  size_t off = 0;
  auto take = [&](size_t bytes) -> char* {
    char* p = ws + off;
    off = (off + bytes + 255) & ~(size_t)255;
    return p;
  };
  u16*   xent  = (u16*)take(NKf * 2);
  u16*   hA    = (u16*)take(NKf * 2);
  u16*   hB    = (u16*)take(NKf * 2);
  float* Sx    = (float*)take(NKf * 4);
  float* Ss    = (float*)take(NKf * 4);
  u16*   Ssb   = (u16*)take(NKf * 2);
  float* semb  = (float*)take((size_t)BB * KK * 4);
  float* cstu  = (float*)take(KK * 4);
  float* cexer = (float*)take(KK * 4);
  u16*   Bsw   = (u16*)take((size_t)3 * 49152 * 2);
  float* bsum  = (float*)take((size_t)3 * KK * 4);
  u32*   degI  = (u32*)take((size_t)3 * NN * 4);
  float* rsdO  = (float*)take((size_t)3 * NN * 4);
  float* rsdI  = (float*)take((size_t)3 * NN * 4);
  u32*   rp    = (u32*)take((size_t)3 * (NN + 1) * 4);
  uint2* edata = (uint2*)take((size_t)3 * EE * 8);
  u32*   slabO = (u32*)take((size_t)3 * NB * NP * 4);
  u32*   slabI = (u32*)take((size_t)3 * NB * NP * 4);
  (void)ws_size; (void)in_sizes; (void)n_in; (void)out_size;

  k_hist<<<dim3(NB, 3), 256, 0, stream>>>(s0, dd0, s1, dd1, s2, dd2, slabO, slabI);
  k_reduce<<<dim3((NP + 255) / 256, 3), 256, 0, stream>>>(slabO, slabI, degI, rsdO, rsdI);
  k_exscan2<<<3, 1024, 0, stream>>>(degI, rp);
  k_scatter2<<<dim3(NB, 3), 256, 0, stream>>>(s0, dd0, s1, dd1, s2, dd2, slabI, rp,
                                              rsdO, rsdI, edata);
  k_prep<<<1106, 256, 0, stream>>>(entity, xent, gcnW, Bsw, gcnB, bsum);

  const u16* xs[3] = {xent, hA, hB};
  u16* outs[3]     = {hA, hB, hA};
  const int modes[3] = {1, 2, 4 | 8};
  for (int l = 0; l < 3; ++l)
    k_layer<<<NN / RPB, 512, 0, stream>>>(xs[l], rp, edata, Bsw + (size_t)l * 49152,
                                          bsum + (size_t)l * KK, outs[l], entity,
                                          Sx, Ss, Ssb, modes[l]);

  k_post<<<544, 256, 0, stream>>>(Ssb, history, hlen, semb, Sx, Wstu, Wexer, cstu, cexer);
  k_final<<<BB * 64 / 256, 256, 0, stream>>>(Sx, semb, cstu, cexer, Wstu, Wexer, W3, disc,
                                             exer_id, kn, bstu, bexer, b3, (float*)d_out);
}

// Round 9
// 184.392 us; speedup vs baseline: 1.4229x; 1.4229x over previous
//
#include <hip/hip_runtime.h>

#define NN 16512      // N = K + EXER nodes
#define KK 128        // feature dim
#define K3 384        // 3 graphs concatenated along K
#define EE 262144     // edges per graph
#define BB 2048       // batch
#define HH 64         // history length
#define NKf ((size_t)NN * KK)
#define NB 64         // hist blocks per graph
#define EPB (EE / NB) // 4096 edges per block
#define NP (NN / 2)   // 8256 packed u16-pair counters
#define RPB 16        // rows per k_layer block
#define CAP 512       // staged edges per graph per block (mean ~254)

typedef unsigned int u32;
typedef unsigned short u16;
typedef short bf16x8 __attribute__((ext_vector_type(8)));
typedef float f32x4 __attribute__((ext_vector_type(4)));

__device__ __forceinline__ float sgm(float x) { return 1.0f / (1.0f + __expf(-x)); }

__device__ __forceinline__ u16 f2bf(float f) {          // round-to-nearest-even
  u32 u = __float_as_uint(f);
  u32 r = u + 0x7fffu + ((u >> 16) & 1u);
  return (u16)(r >> 16);
}
__device__ __forceinline__ float bflo(u32 p) { return __uint_as_float(p << 16); }
__device__ __forceinline__ float bfhi(u32 p) { return __uint_as_float(p & 0xffff0000u); }

// ---------------- graph preprocessing (atomic-free counting sort) ----------------

__global__ __launch_bounds__(256) void k_hist(
    const int* __restrict__ s0, const int* __restrict__ d0,
    const int* __restrict__ s1, const int* __restrict__ d1,
    const int* __restrict__ s2, const int* __restrict__ d2,
    u32* __restrict__ slabO, u32* __restrict__ slabI) {
  int g = blockIdx.y, b = blockIdx.x;
  const int* src = g == 0 ? s0 : (g == 1 ? s1 : s2);
  const int* dst = g == 0 ? d0 : (g == 1 ? d1 : d2);
  __shared__ u32 hO[NP], hI[NP];
  for (int i = threadIdx.x; i < NP; i += 256) { hO[i] = 0; hI[i] = 0; }
  __syncthreads();
  int base = b * EPB;
  for (int i = threadIdx.x; i < EPB; i += 256) {
    int s = src[base + i], d = dst[base + i];
    atomicAdd(&hO[s >> 1], 1u << ((s & 1) * 16));
    atomicAdd(&hI[d >> 1], 1u << ((d & 1) * 16));
  }
  __syncthreads();
  u32* oO = slabO + ((size_t)g * NB + b) * NP;
  u32* oI = slabI + ((size_t)g * NB + b) * NP;
  for (int i = threadIdx.x; i < NP; i += 256) { oO[i] = hO[i]; oI[i] = hI[i]; }
}

__global__ void k_reduce(u32* __restrict__ slabO, u32* __restrict__ slabI,
                         u32* __restrict__ degI, float* __restrict__ rsdO,
                         float* __restrict__ rsdI) {
  int g = blockIdx.y;
  int t = blockIdx.x * 256 + threadIdx.x;
  if (t >= NP) return;
  u32* sO = slabO + (size_t)g * NB * NP + t;
  u32* sI = slabI + (size_t)g * NB * NP + t;
  u32 sumO = 0, pre = 0;
  #pragma unroll 8
  for (int b = 0; b < NB; ++b) sumO += sO[(size_t)b * NP];
  #pragma unroll 8
  for (int b = 0; b < NB; ++b) {
    u32 v = sI[(size_t)b * NP];
    sI[(size_t)b * NP] = pre;          // packed u16 exclusive prefix
    pre += v;
  }
  u32 dOl = sumO & 0xffffu, dOh = sumO >> 16;
  u32 dIl = pre & 0xffffu,  dIh = pre >> 16;
  *(uint2*)(degI + (size_t)g * NN + 2 * t) = make_uint2(dIl, dIh);
  *(float2*)(rsdO + (size_t)g * NN + 2 * t) =
      make_float2(rsqrtf((float)(dOl ? dOl : 1u)), rsqrtf((float)(dOh ? dOh : 1u)));
  *(float2*)(rsdI + (size_t)g * NN + 2 * t) =
      make_float2(rsqrtf((float)(dIl ? dIl : 1u)), rsqrtf((float)(dIh ? dIh : 1u)));
}

__global__ __launch_bounds__(1024) void k_exscan2(const u32* __restrict__ degI,
                                                  u32* __restrict__ rps) {
  int g = blockIdx.x;
  const u32* deg = degI + (size_t)g * NN;
  u32* rp = rps + (size_t)g * (NN + 1);
  int t = threadIdx.x;
  int i0 = t * 17, i1 = i0 + 17 < NN ? i0 + 17 : NN;
  u32 s = 0;
  for (int i = i0; i < i1; ++i) s += deg[i];
  u32 x = s;
  int lane = t & 63, wid = t >> 6;
  #pragma unroll
  for (int off = 1; off < 64; off <<= 1) {
    u32 y = __shfl_up(x, off);
    if (lane >= off) x += y;
  }
  __shared__ u32 wsums[16];
  if (lane == 63) wsums[wid] = x;
  __syncthreads();
  if (t == 0) {
    u32 run = 0;
    #pragma unroll
    for (int i = 0; i < 16; ++i) { u32 tmp = wsums[i]; wsums[i] = run; run += tmp; }
  }
  __syncthreads();
  u32 run = wsums[wid] + x - s;
  for (int i = i0; i < i1; ++i) { rp[i] = run; run += deg[i]; }
  if (t == 0) rp[NN] = EE;
}

// edata[idx] = { src, norm(f32) } -> single 8B store per edge
__global__ __launch_bounds__(256) void k_scatter2(
    const int* __restrict__ s0, const int* __restrict__ d0,
    const int* __restrict__ s1, const int* __restrict__ d1,
    const int* __restrict__ s2, const int* __restrict__ d2,
    const u32* __restrict__ slabI, const u32* __restrict__ rps,
    const float* __restrict__ rsdO, const float* __restrict__ rsdI,
    uint2* __restrict__ edatas) {
  int g = blockIdx.y, b = blockIdx.x;
  const int* src = g == 0 ? s0 : (g == 1 ? s1 : s2);
  const int* dst = g == 0 ? d0 : (g == 1 ? d1 : d2);
  const u32* rp = rps + (size_t)g * (NN + 1);
  const u32* pre = slabI + ((size_t)g * NB + b) * NP;
  const float* rO = rsdO + (size_t)g * NN;
  const float* rI = rsdI + (size_t)g * NN;
  uint2* ed = edatas + (size_t)g * EE;
  __shared__ u32 cur[NN];
  for (int i = threadIdx.x; i < NP; i += 256) {
    u32 p = pre[i];
    cur[2 * i]     = rp[2 * i] + (p & 0xffffu);
    cur[2 * i + 1] = rp[2 * i + 1] + (p >> 16);
  }
  __syncthreads();
  int base = b * EPB;
  for (int i = threadIdx.x; i < EPB; i += 256) {
    int s = src[base + i], d = dst[base + i];
    u32 idx = atomicAdd(&cur[d], 1u);
    ed[idx] = make_uint2((u32)s, __float_as_uint(rO[s] * rI[d]));
  }
}

// ---------------- fused prep: entity->bf16 | W pre-swizzle | bias sums ----------------
// Bsw[((l*96 + nb*12 + ks)*64 + lane)*8 + j] = bf16( W[l, g, kin, kout] )
//   k = ks*32 + (lane>>4)*8 + j ; g = k>>7 ; kin = k&127 ; kout = nb*16 + (lane&15)

__global__ void k_prep(const float* __restrict__ entity, u16* __restrict__ xent,
                       const float* __restrict__ W, u16* __restrict__ Bsw,
                       const float* __restrict__ b, float* __restrict__ bsum) {
  int bid = blockIdx.x;
  if (bid < 1032) {                       // cvt: NN*KK/8 = 264192 items
    int t = bid * 256 + threadIdx.x;
    if (t >= NN * KK / 8) return;
    const float4* p = (const float4*)entity + (size_t)t * 2;
    float4 v0 = p[0], v1 = p[1];
    bf16x8 o;
    o[0] = (short)f2bf(v0.x); o[1] = (short)f2bf(v0.y);
    o[2] = (short)f2bf(v0.z); o[3] = (short)f2bf(v0.w);
    o[4] = (short)f2bf(v1.x); o[5] = (short)f2bf(v1.y);
    o[6] = (short)f2bf(v1.z); o[7] = (short)f2bf(v1.w);
    *(bf16x8*)(xent + (size_t)t * 8) = o;
  } else if (bid < 1104) {                // prepB: 18432 items
    int t = (bid - 1032) * 256 + threadIdx.x;
    if (t >= 3 * 8 * 12 * 64) return;
    int lane = t & 63;
    int ks = (t >> 6) % 12;
    int nb = ((t >> 6) / 12) % 8;
    int l  = (t >> 6) / 96;
    int kout = nb * 16 + (lane & 15);
    int kb = ks * 32 + (lane >> 4) * 8;
    bf16x8 v;
    #pragma unroll
    for (int j = 0; j < 8; ++j) {
      int k = kb + j; int g = k >> 7; int kin = k & 127;
      v[j] = (short)f2bf(W[(((size_t)l * 3 + g) * KK + kin) * KK + kout]);
    }
    *(bf16x8*)(Bsw + (size_t)t * 8) = v;
  } else {                                // bias sums: 384 items
    int t = (bid - 1104) * 256 + threadIdx.x;
    if (t >= 3 * KK) return;
    int l = t >> 7, c = t & 127;
    bsum[l * KK + c] = b[(l * 3 + 0) * KK + c] + b[(l * 3 + 1) * KK + c] + b[(l * 3 + 2) * KK + c];
  }
}

// ---------------- fused layer: SpMM (3 graphs -> LDS) + MFMA GEMM + epilogue ----------
// Block owns 16 rows; 8 waves; 48 row-tasks processed as 24 PAIRS (2 independent
// gather chains per wave -> 2x MLP). Edge meta staged in LDS (global fallback).
// mode: 1 = Sx = entity + v ; else Sx += v
//       2 = Ss = v ; 4 = Ssb = bf16(Ss + v) ; 8 = skip h write

#define ACC8(A, P, N)                                              \
  A[0] += bflo(P.x) * N; A[1] += bfhi(P.x) * N;                    \
  A[2] += bflo(P.y) * N; A[3] += bfhi(P.y) * N;                    \
  A[4] += bflo(P.z) * N; A[5] += bfhi(P.z) * N;                    \
  A[6] += bflo(P.w) * N; A[7] += bfhi(P.w) * N;

#define ONE(MP, E, A) {                                            \
    uint2 m = MP[E + slot];                                        \
    float n = __uint_as_float(m.y);                                \
    uint4 p = *(const uint4*)(x + (size_t)m.x * KK + cg * 8);      \
    ACC8(A, p, n) }

__global__ __launch_bounds__(512) void k_layer(
    const u16* __restrict__ x, const u32* __restrict__ rps,
    const uint2* __restrict__ edatas, const u16* __restrict__ Bsw,
    const float* __restrict__ bsum, u16* __restrict__ hout,
    const float* __restrict__ entity, float* __restrict__ Sx,
    float* __restrict__ Ss, u16* __restrict__ Ssb, int mode)
{
  __shared__ u16 At[RPB][392];            // 12.25 KB; row stride 784B -> 2-way (free)
  __shared__ uint2 meta[3][CAP];          // 12 KB staged edge metadata
  __shared__ u32 rpl[3][RPB + 1];         // row pointers
  const int tid = threadIdx.x;
  const int wv = tid >> 6, lane = tid & 63;
  const int m0 = blockIdx.x * RPB;
  const int slot = lane >> 4, cg = lane & 15;

  if (tid < 3 * (RPB + 1))
    rpl[tid / (RPB + 1)][tid % (RPB + 1)] =
        rps[(size_t)(tid / (RPB + 1)) * (NN + 1) + m0 + tid % (RPB + 1)];
  __syncthreads();

  // ---- stage edge metadata (contiguous CSR slices) ----
  #pragma unroll
  for (int g = 0; g < 3; ++g) {
    u32 b0 = rpl[g][0];
    u32 cnt = rpl[g][RPB] - b0; if (cnt > CAP) cnt = CAP;
    const uint2* ed = edatas + (size_t)g * EE + b0;
    for (u32 i = tid; i < cnt; i += 512) meta[g][i] = ed[i];
  }
  __syncthreads();

  // ---- SpMM phase: 24 pairs, 2 independent chains per wave ----
  for (int p = wv; p < 24; p += 8) {
    int tA = p, tB = p + 24;
    int gA = tA >> 4, rA = tA & 15;
    int gB = tB >> 4, rB = tB & 15;
    u32 begA = rpl[gA][rA], cntA = rpl[gA][rA + 1] - begA;
    u32 begB = rpl[gB][rB], cntB = rpl[gB][rB + 1] - begB;
    const uint2* mpA = (rpl[gA][RPB] - rpl[gA][0] <= CAP)
                           ? &meta[gA][begA - rpl[gA][0]]
                           : edatas + (size_t)gA * EE + begA;
    const uint2* mpB = (rpl[gB][RPB] - rpl[gB][0] <= CAP)
                           ? &meta[gB][begB - rpl[gB][0]]
                           : edatas + (size_t)gB * EE + begB;
    float accA[8] = {0.f, 0.f, 0.f, 0.f, 0.f, 0.f, 0.f, 0.f};
    float accB[8] = {0.f, 0.f, 0.f, 0.f, 0.f, 0.f, 0.f, 0.f};
    u32 qA = cntA & ~3u, qB = cntB & ~3u;
    u32 qm = qA < qB ? qA : qB;
    u32 eA = 0, eB = 0;
    for (; eA < qm; eA += 4, eB += 4) {
      uint2 mA = mpA[eA + slot];
      uint2 mB = mpB[eB + slot];
      uint4 pA = *(const uint4*)(x + (size_t)mA.x * KK + cg * 8);
      uint4 pB = *(const uint4*)(x + (size_t)mB.x * KK + cg * 8);
      float nA = __uint_as_float(mA.y), nB = __uint_as_float(mB.y);
      ACC8(accA, pA, nA) ACC8(accB, pB, nB)
    }
    for (; eA < qA; eA += 4) ONE(mpA, eA, accA)
    for (; eB < qB; eB += 4) ONE(mpB, eB, accB)
    if (eA + slot < cntA) ONE(mpA, eA, accA)
    if (eB + slot < cntB) ONE(mpB, eB, accB)
    #pragma unroll
    for (int i = 0; i < 8; ++i) {
      accA[i] += __shfl_xor(accA[i], 16); accA[i] += __shfl_xor(accA[i], 32);
      accB[i] += __shfl_xor(accB[i], 16); accB[i] += __shfl_xor(accB[i], 32);
    }
    if (slot == 0) {
      u32 a0 = ((u32)f2bf(accA[1]) << 16) | (u32)f2bf(accA[0]);
      u32 a1 = ((u32)f2bf(accA[3]) << 16) | (u32)f2bf(accA[2]);
      u32 a2 = ((u32)f2bf(accA[5]) << 16) | (u32)f2bf(accA[4]);
      u32 a3 = ((u32)f2bf(accA[7]) << 16) | (u32)f2bf(accA[6]);
      *(uint4*)(&At[rA][gA * KK + cg * 8]) = make_uint4(a0, a1, a2, a3);
      u32 b0 = ((u32)f2bf(accB[1]) << 16) | (u32)f2bf(accB[0]);
      u32 b1 = ((u32)f2bf(accB[3]) << 16) | (u32)f2bf(accB[2]);
      u32 b2 = ((u32)f2bf(accB[5]) << 16) | (u32)f2bf(accB[4]);
      u32 b3 = ((u32)f2bf(accB[7]) << 16) | (u32)f2bf(accB[6]);
      *(uint4*)(&At[rB][gB * KK + cg * 8]) = make_uint4(b0, b1, b2, b3);
    }
  }
  __syncthreads();

  // ---- MFMA phase: 16x128 = At(16x384) @ B(384x128); wave wv -> cols wv*16.. ----
  const int lr = lane & 15, lk = lane >> 4;
  f32x4 acc2 = {0.f, 0.f, 0.f, 0.f};
  const u16* aB = Bsw + (size_t)wv * 6144 + (size_t)lane * 8;
  #pragma unroll
  for (int ks = 0; ks < 12; ++ks) {
    bf16x8 a = *(const bf16x8*)(&At[lr][ks * 32 + lk * 8]);
    bf16x8 b = *(const bf16x8*)(aB + ks * 512);
    acc2 = __builtin_amdgcn_mfma_f32_16x16x32_bf16(a, b, acc2, 0, 0, 0);
  }

  int col = wv * 16 + lr;
  float bv = bsum[col];
  int rowb = m0 + lk * 4;
  #pragma unroll
  for (int r = 0; r < 4; ++r) {
    size_t idx = (size_t)(rowb + r) * KK + col;
    float v = acc2[r] + bv;
    if (!(mode & 8)) hout[idx] = f2bf(v);
    float sx = (mode & 1) ? (entity[idx] + v) : (Sx[idx] + v);
    Sx[idx] = sx;
    if (mode & 2) Ss[idx] = v;
    else if (mode & 4) Ssb[idx] = f2bf(Ss[idx] + v);
  }
}

// ---------------- fused post: history mean (quad rows) + concept projections ----------

__global__ __launch_bounds__(256) void k_post(
    const u16* __restrict__ Ssb, const int* __restrict__ hist, const int* __restrict__ hlen,
    float* __restrict__ semb, const float* __restrict__ Sx,
    const float* __restrict__ Wstu, const float* __restrict__ Wexer,
    float* __restrict__ cstu, float* __restrict__ cexer)
{
  int wv = threadIdx.x >> 6, lane = threadIdx.x & 63;
  if (blockIdx.x < 512) {                 // stuemb: 2048 items
    int item = blockIdx.x * 4 + wv;
    int slot = lane >> 4, cg = lane & 15;
    int len = hlen[item];
    const int* hrow = hist + item * HH;
    float acc[8] = {0.f, 0.f, 0.f, 0.f, 0.f, 0.f, 0.f, 0.f};
    int h = 0;
    for (; h + 4 <= len; h += 4) {
      int id = hrow[h + slot];
      uint4 p = *(const uint4*)(Ssb + (size_t)(KK + id) * KK + cg * 8);
      acc[0] += bflo(p.x); acc[1] += bfhi(p.x);
      acc[2] += bflo(p.y); acc[3] += bfhi(p.y);
      acc[4] += bflo(p.z); acc[5] += bfhi(p.z);
      acc[6] += bflo(p.w); acc[7] += bfhi(p.w);
    }
    if (h + slot < len) {
      int id = hrow[h + slot];
      uint4 p = *(const uint4*)(Ssb + (size_t)(KK + id) * KK + cg * 8);
      acc[0] += bflo(p.x); acc[1] += bfhi(p.x);
      acc[2] += bflo(p.y); acc[3] += bfhi(p.y);
      acc[4] += bflo(p.z); acc[5] += bfhi(p.z);
      acc[6] += bflo(p.w); acc[7] += bfhi(p.w);
    }
    #pragma unroll
    for (int i = 0; i < 8; ++i) {
      acc[i] += __shfl_xor(acc[i], 16);
      acc[i] += __shfl_xor(acc[i], 32);
    }
    if (slot == 0) {
      float sc = 0.5f / (float)len;
      float4 o0 = make_float4(acc[0] * sc, acc[1] * sc, acc[2] * sc, acc[3] * sc);
      float4 o1 = make_float4(acc[4] * sc, acc[5] * sc, acc[6] * sc, acc[7] * sc);
      *(float4*)(semb + (size_t)item * KK + cg * 8) = o0;
      *(float4*)(semb + (size_t)item * KK + cg * 8 + 4) = o1;
    }
  } else {                                // cproj: 128 concept rows
    int w = (blockIdx.x - 512) * 4 + wv;
    float2 c = *(const float2*)(Sx + (size_t)w * KK + lane * 2);
    c.x *= 0.25f; c.y *= 0.25f;
    float2 ws = *(const float2*)(Wstu + KK + lane * 2);
    float2 we = *(const float2*)(Wexer + KK + lane * 2);
    float ps = c.x * ws.x + c.y * ws.y;
    float pe = c.x * we.x + c.y * we.y;
    #pragma unroll
    for (int off = 32; off; off >>= 1) { ps += __shfl_xor(ps, off); pe += __shfl_xor(pe, off); }
    if (lane == 0) { cstu[w] = ps; cexer[w] = pe; }
  }
}

__global__ void k_final(const float* __restrict__ Sx, const float* __restrict__ semb,
                        const float* __restrict__ cstu, const float* __restrict__ cexer,
                        const float* __restrict__ Wstu, const float* __restrict__ Wexer,
                        const float* __restrict__ W3, const float* __restrict__ disc,
                        const int* __restrict__ exid, const float* __restrict__ kn,
                        const float* __restrict__ bstu, const float* __restrict__ bexer,
                        const float* __restrict__ b3, float* __restrict__ out) {
  int w = (blockIdx.x * 256 + threadIdx.x) >> 6;   // batch index
  int lane = threadIdx.x & 63;
  if (w >= BB) return;
  int eid = exid[w];
  float2 se = *(const float2*)(Sx + ((size_t)(KK + eid)) * KK + lane * 2);
  se.x *= 0.25f; se.y *= 0.25f;                    // exer_emb
  float2 sm = *(const float2*)(semb + (size_t)w * KK + lane * 2);
  float2 ws = *(const float2*)(Wstu + lane * 2);
  float2 we = *(const float2*)(Wexer + lane * 2);
  float ps = sm.x * ws.x + sm.y * ws.y;
  float pe = se.x * we.x + se.y * we.y;
  #pragma unroll
  for (int off = 32; off; off >>= 1) { ps += __shfl_xor(ps, off); pe += __shfl_xor(pe, off); }
  float s_stu = ps + bstu[0];
  float s_exer = pe + bexer[0];
  float ed = 10.f * sgm(disc[eid]);
  float2 cs = *(const float2*)(cstu + lane * 2);
  float2 ce = *(const float2*)(cexer + lane * 2);
  float2 knv = *(const float2*)(kn + (size_t)w * KK + lane * 2);
  float x0 = ed * (sgm(s_stu + cs.x) - sgm(s_exer + ce.x)) * knv.x;
  float x1 = ed * (sgm(s_stu + cs.y) - sgm(s_exer + ce.y)) * knv.y;
  float2 w3v = *(const float2*)(W3 + lane * 2);
  float px = x0 * w3v.x + x1 * w3v.y;
  #pragma unroll
  for (int off = 32; off; off >>= 1) px += __shfl_xor(px, off);
  if (lane == 0) out[w] = sgm(px + b3[0]);
}

// ---------------- host ----------------

extern "C" void kernel_launch(void* const* d_in, const int* in_sizes, int n_in,
                              void* d_out, int out_size, void* d_ws, size_t ws_size,
                              hipStream_t stream)
{
  const float* entity = (const float*)d_in[0];
  const float* gcnW   = (const float*)d_in[1];
  const float* gcnB   = (const float*)d_in[2];
  const float* disc   = (const float*)d_in[3];
  const float* Wstu   = (const float*)d_in[4];
  const float* bstu   = (const float*)d_in[5];
  const float* Wexer  = (const float*)d_in[6];
  const float* bexer  = (const float*)d_in[7];
  const float* W3     = (const float*)d_in[8];
  const float* b3     = (const float*)d_in[9];
  const float* kn     = (const float*)d_in[10];
  const int* exer_id  = (const int*)d_in[12];
  const int* history  = (const int*)d_in[14];
  const int* hlen     = (const int*)d_in[15];
  const int* s0 = (const int*)d_in[16], *dd0 = (const int*)d_in[17];
  const int* s1 = (const int*)d_in[18], *dd1 = (const int*)d_in[19];
  const int* s2 = (const int*)d_in[20], *dd2 = (const int*)d_in[21];

  char* ws = (char*)d_ws;
  size_t off = 0;
  auto take = [&](size_t bytes) -> char* {
    char* p = ws + off;
    off = (off + bytes + 255) & ~(size_t)255;
    return p;
  };
  u16*   xent  = (u16*)take(NKf * 2);
  u16*   hA    = (u16*)take(NKf * 2);
  u16*   hB    = (u16*)take(NKf * 2);
  float* Sx    = (float*)take(NKf * 4);
  float* Ss    = (float*)take(NKf * 4);
  u16*   Ssb   = (u16*)take(NKf * 2);
  float* semb  = (float*)take((size_t)BB * KK * 4);
  float* cstu  = (float*)take(KK * 4);
  float* cexer = (float*)take(KK * 4);
  u16*   Bsw   = (u16*)take((size_t)3 * 49152 * 2);
  float* bsum  = (float*)take((size_t)3 * KK * 4);
  u32*   degI  = (u32*)take((size_t)3 * NN * 4);
  float* rsdO  = (float*)take((size_t)3 * NN * 4);
  float* rsdI  = (float*)take((size_t)3 * NN * 4);
  u32*   rp    = (u32*)take((size_t)3 * (NN + 1) * 4);
  uint2* edata = (uint2*)take((size_t)3 * EE * 8);
  u32*   slabO = (u32*)take((size_t)3 * NB * NP * 4);
  u32*   slabI = (u32*)take((size_t)3 * NB * NP * 4);
  (void)ws_size; (void)in_sizes; (void)n_in; (void)out_size;

  k_hist<<<dim3(NB, 3), 256, 0, stream>>>(s0, dd0, s1, dd1, s2, dd2, slabO, slabI);
  k_reduce<<<dim3((NP + 255) / 256, 3), 256, 0, stream>>>(slabO, slabI, degI, rsdO, rsdI);
  k_exscan2<<<3, 1024, 0, stream>>>(degI, rp);
  k_scatter2<<<dim3(NB, 3), 256, 0, stream>>>(s0, dd0, s1, dd1, s2, dd2, slabI, rp,
                                              rsdO, rsdI, edata);
  k_prep<<<1106, 256, 0, stream>>>(entity, xent, gcnW, Bsw, gcnB, bsum);

  const u16* xs[3] = {xent, hA, hB};
  u16* outs[3]     = {hA, hB, hA};
  const int modes[3] = {1, 2, 4 | 8};
  for (int l = 0; l < 3; ++l)
    k_layer<<<NN / RPB, 512, 0, stream>>>(xs[l], rp, edata, Bsw + (size_t)l * 49152,
                                          bsum + (size_t)l * KK, outs[l], entity,
                                          Sx, Ss, Ssb, modes[l]);

  k_post<<<544, 256, 0, stream>>>(Ssb, history, hlen, semb, Sx, Wstu, Wexer, cstu, cexer);
  k_final<<<BB * 64 / 256, 256, 0, stream>>>(Sx, semb, cstu, cexer, Wstu, Wexer, W3, disc,
                                             exer_id, kn, bstu, bexer, b3, (float*)d_out);
}